// Round 1
// baseline (955.654 us; speedup 1.0000x reference)
//
#include <hip/hip_runtime.h>

#define NCH 64     // p = channels = number of networks
#define LAG 5
#define H0 32
#define H1 32
#define TIN 2048
#define TOUT 2044  // TIN - LAG + 1
#define NBATCH 16
#define NPOS (NBATCH*TOUT)  // 32704

// One block: network n = blockIdx.y, 256 consecutive (b,t) positions.
// Weights for network n staged in LDS, transposed so the h-loop reads
// contiguous (broadcast) b128 words. X read from global (L2-resident, float4).
__global__ __launch_bounds__(256) void cmlp_fused(
    const float* __restrict__ X, const float* __restrict__ W0,
    const float* __restrict__ b0, const float* __restrict__ W1,
    const float* __restrict__ b1, const float* __restrict__ W2,
    const float* __restrict__ b2, float* __restrict__ out)
{
    __shared__ float w0s[LAG*NCH*H0];  // [(l*64 + c)*32 + h]  = 40 KB
    __shared__ float w1s[H0*H1];       // [i*32 + o]           = 4 KB
    __shared__ float w2s[H1];
    __shared__ float b0s[H0];
    __shared__ float b1s[H1];
    __shared__ float b2s;

    const int n   = blockIdx.y;
    const int tid = threadIdx.x;

    // --- stage weights (coalesced global reads, scattered LDS writes) ---
    const float* W0n = W0 + n*(H0*NCH*LAG);          // src layout [h][c][l]
    for (int s = tid; s < H0*NCH*LAG; s += 256) {
        int h = s / (NCH*LAG);
        int r = s - h*(NCH*LAG);
        int c = r / LAG;
        int l = r - c*LAG;
        w0s[(l*NCH + c)*H0 + h] = W0n[s];
    }
    const float* W1n = W1 + n*(H1*H0);               // src layout [o][i]
    for (int s = tid; s < H1*H0; s += 256) {
        int o = s / H0, i = s - o*H0;
        w1s[i*H1 + o] = W1n[s];
    }
    if (tid < H1) w2s[tid] = W2[n*H1 + tid];
    if (tid < H0) b0s[tid] = b0[n*H0 + tid];
    if (tid < H1) b1s[tid] = b1[n*H1 + tid];
    if (tid == 0) b2s = b2[n];
    __syncthreads();

    const int pos = blockIdx.x*256 + tid;
    if (pos >= NPOS) return;   // no barriers after this point
    const int b = pos / TOUT;
    const int t = pos - b*TOUT;

    // --- layer 0: conv(p=64, h0=32, lag=5) ---
    float acc[H0];
#pragma unroll
    for (int h = 0; h < H0; ++h) acc[h] = b0s[h];

    const float* xbase = X + (b*TIN + t)*NCH;   // 256B-aligned
#pragma unroll 1
    for (int l = 0; l < LAG; ++l) {
        const float4* xr = (const float4*)(xbase + l*NCH);
        const float*  wl = w0s + l*NCH*H0;
#pragma unroll 2
        for (int cq = 0; cq < NCH/4; ++cq) {
            float4 x = xr[cq];
            const float* wp = wl + cq*4*H0;
#pragma unroll
            for (int h = 0; h < H0; ++h) {
                acc[h] += x.x*wp[h] + x.y*wp[H0 + h]
                        + x.z*wp[2*H0 + h] + x.w*wp[3*H0 + h];
            }
        }
    }

    // --- layer 1: relu -> dense 32x32 ---
    float acc1[H1];
#pragma unroll
    for (int o = 0; o < H1; ++o) acc1[o] = b1s[o];
#pragma unroll 4
    for (int i = 0; i < H0; ++i) {
        float hv = fmaxf(acc[i], 0.0f);
#pragma unroll
        for (int o = 0; o < H1; ++o) acc1[o] += hv * w1s[i*H1 + o];
    }

    // --- layer 2: relu -> dense 32x1 ---
    float y = b2s;
#pragma unroll
    for (int o = 0; o < H1; ++o) y += fmaxf(acc1[o], 0.0f) * w2s[o];

    out[pos*NCH + n] = y;   // out[b][t][n]
}

extern "C" void kernel_launch(void* const* d_in, const int* in_sizes, int n_in,
                              void* d_out, int out_size, void* d_ws, size_t ws_size,
                              hipStream_t stream)
{
    const float* X  = (const float*)d_in[0];
    const float* W0 = (const float*)d_in[1];
    const float* b0 = (const float*)d_in[2];
    const float* W1 = (const float*)d_in[3];
    const float* b1 = (const float*)d_in[4];
    const float* W2 = (const float*)d_in[5];
    const float* b2 = (const float*)d_in[6];
    float* out = (float*)d_out;

    dim3 grid((NPOS + 255)/256, NCH);
    cmlp_fused<<<grid, dim3(256), 0, stream>>>(X, W0, b0, W1, b1, W2, b2, out);
}

// Round 2
// 305.248 us; speedup vs baseline: 3.1308x; 3.1308x over previous
//
#include <hip/hip_runtime.h>

#define NCH 64
#define LAG 5
#define H0 32
#define H1 32
#define TIN 2048
#define TOUT 2044
#define NBATCH 16
#define NPOS (NBATCH*TOUT)   // 32704
#define MPAD 32768           // yT row stride (per network)

typedef __attribute__((ext_vector_type(8))) short short8;   // 8 bf16 = 4 VGPRs
typedef __attribute__((ext_vector_type(4))) float f32x4;

__device__ __forceinline__ unsigned short f2bf(float f) {
    unsigned u = __float_as_uint(f);
    u += 0x7fffu + ((u >> 16) & 1u);     // RNE
    return (unsigned short)(u >> 16);
}

// ---- prep: X fp32 -> bf16 (same layout) ----
__global__ __launch_bounds__(256) void prep_x(const float* __restrict__ X,
                                              unsigned short* __restrict__ Xb) {
    int i = (blockIdx.x * 256 + threadIdx.x) * 4;   // total 2,097,152 elems
    float4 x = *(const float4*)(X + i);
    unsigned long long v = (unsigned long long)f2bf(x.x)
                         | ((unsigned long long)f2bf(x.y) << 16)
                         | ((unsigned long long)f2bf(x.z) << 32)
                         | ((unsigned long long)f2bf(x.w) << 48);
    *(unsigned long long*)(Xb + i) = v;
}

// ---- prep: W0 [n][h][c][l] fp32 -> W0b [n*32+h][k=l*64+c] bf16 ----
__global__ __launch_bounds__(256) void prep_w0(const float* __restrict__ W0,
                                               unsigned short* __restrict__ W0b) {
    int i = blockIdx.x * 256 + threadIdx.x;         // 655,360 elems
    int l = i % 5;
    int r = i / 5;
    int c = r & 63;
    int nh = r >> 6;
    W0b[nh * 320 + l * 64 + c] = f2bf(W0[i]);
}

// ---- prep: W1 [n][o][i] fp32 -> bf16 (same layout) ----
__global__ __launch_bounds__(256) void prep_w1(const float* __restrict__ W1,
                                               unsigned short* __restrict__ W1b) {
    int i = blockIdx.x * 256 + threadIdx.x;         // 65,536 elems
    W1b[i] = f2bf(W1[i]);
}

// ---- main: one block = network n (blockIdx.x) x 256 positions (blockIdx.y) ----
__global__ __launch_bounds__(256) void mlp_mfma(
    const unsigned short* __restrict__ Xb,
    const unsigned short* __restrict__ W0b,
    const unsigned short* __restrict__ W1b,
    const float* __restrict__ b0, const float* __restrict__ b1,
    const float* __restrict__ W2, const float* __restrict__ b2,
    float* __restrict__ yT, float* __restrict__ out)
{
    const int n    = blockIdx.x;
    const int tile = blockIdx.y;
    const int wave = threadIdx.x >> 6;
    const int lane = threadIdx.x & 63;
    const int quad = lane >> 4;
    const int l15  = lane & 15;

    // per-wave relayout buffer: row stride 56 ushort = 112 B (16B-aligned rows,
    // banks: reads m*28+q*4 mod 32 -> 2-way (free); writes quad offsets {0,16,0,16} -> 2-way
    __shared__ __align__(16) unsigned short hs[4][64][56];   // 28,672 B

    // ---- preload all B fragments into registers ----
    short8 B0[10][2];
    {
        const unsigned short* wp = W0b + (n * H0 + l15) * (NCH * LAG) + quad * 8;
        #pragma unroll
        for (int ks = 0; ks < 10; ++ks) {
            B0[ks][0] = *(const short8*)(wp + ks * 32);
            B0[ks][1] = *(const short8*)(wp + 16 * (NCH * LAG) + ks * 32);
        }
    }
    short8 B1[2];
    {
        const unsigned short* wp = W1b + (n * H1 + l15) * H0 + quad * 8;
        B1[0] = *(const short8*)(wp);
        B1[1] = *(const short8*)(wp + 16 * H0);
    }
    float b0v[2] = { b0[n * H0 + l15], b0[n * H0 + 16 + l15] };
    float b1v[2] = { b1[n * H1 + l15], b1[n * H1 + 16 + l15] };
    float w2v[2] = { W2[n * H1 + l15], W2[n * H1 + 16 + l15] };
    float b2s = b2[n];

    const int p0 = tile * 256 + wave * 64;

    // per-m-frag X row base (lane's row m = lane&15), clamped for the tail tile
    const unsigned short* arow[4];
    #pragma unroll
    for (int mf = 0; mf < 4; ++mf) {
        int pos = p0 + mf * 16 + l15;
        pos = pos < NPOS ? pos : NPOS - 1;
        int b = pos / TOUT;
        int t = pos - b * TOUT;
        arow[mf] = Xb + (b * TIN + t) * NCH + quad * 8;
    }

    // ---- layer 0: [M x 320] x [320 x 32], bias in accumulator init ----
    f32x4 acc[4][2];
    #pragma unroll
    for (int mf = 0; mf < 4; ++mf) {
        acc[mf][0] = (f32x4){ b0v[0], b0v[0], b0v[0], b0v[0] };
        acc[mf][1] = (f32x4){ b0v[1], b0v[1], b0v[1], b0v[1] };
    }
    #pragma unroll
    for (int ks = 0; ks < 10; ++ks) {
        const int off = (ks >> 1) * NCH + (ks & 1) * 32;   // k = l*64 + c
        #pragma unroll
        for (int mf = 0; mf < 4; ++mf) {
            short8 A = *(const short8*)(arow[mf] + off);
            acc[mf][0] = __builtin_amdgcn_mfma_f32_16x16x32_bf16(A, B0[ks][0], acc[mf][0], 0, 0, 0);
            acc[mf][1] = __builtin_amdgcn_mfma_f32_16x16x32_bf16(A, B0[ks][1], acc[mf][1], 0, 0, 0);
        }
    }

    // ---- relu -> bf16 -> LDS (C-layout -> A-layout round trip, per-wave) ----
    #pragma unroll
    for (int mf = 0; mf < 4; ++mf)
        #pragma unroll
        for (int nf = 0; nf < 2; ++nf)
            #pragma unroll
            for (int r = 0; r < 4; ++r) {
                float v = fmaxf(acc[mf][nf][r], 0.0f);
                hs[wave][mf * 16 + quad * 4 + r][nf * 16 + l15] = f2bf(v);
            }

    // ---- layer 1: [M x 32] x [32 x 32] ----
    f32x4 acc1[4][2];
    #pragma unroll
    for (int mf = 0; mf < 4; ++mf) {
        acc1[mf][0] = (f32x4){ b1v[0], b1v[0], b1v[0], b1v[0] };
        acc1[mf][1] = (f32x4){ b1v[1], b1v[1], b1v[1], b1v[1] };
    }
    #pragma unroll
    for (int mf = 0; mf < 4; ++mf) {
        short8 A1 = *(const short8*)&hs[wave][mf * 16 + l15][quad * 8];
        acc1[mf][0] = __builtin_amdgcn_mfma_f32_16x16x32_bf16(A1, B1[0], acc1[mf][0], 0, 0, 0);
        acc1[mf][1] = __builtin_amdgcn_mfma_f32_16x16x32_bf16(A1, B1[1], acc1[mf][1], 0, 0, 0);
    }

    // ---- layer 2: relu -> dot(32) via VALU + quad shuffle-reduce ----
    #pragma unroll
    for (int mf = 0; mf < 4; ++mf)
        #pragma unroll
        for (int r = 0; r < 4; ++r) {
            float v = fmaxf(acc1[mf][0][r], 0.0f) * w2v[0]
                    + fmaxf(acc1[mf][1][r], 0.0f) * w2v[1];
            v += __shfl_xor(v, 1, 64);
            v += __shfl_xor(v, 2, 64);
            v += __shfl_xor(v, 4, 64);
            v += __shfl_xor(v, 8, 64);
            v += b2s;
            int pos = p0 + mf * 16 + quad * 4 + r;
            if (l15 == 0 && pos < NPOS) {
                if (yT) yT[n * MPAD + pos] = v;
                else    out[pos * NCH + n] = v;
            }
        }
}

// ---- epilogue: yT[n][pos] -> out[pos][n], 64x64 LDS tiles ----
__global__ __launch_bounds__(256) void transpose_out(const float* __restrict__ yT,
                                                     float* __restrict__ out) {
    __shared__ float ts[64][65];
    const int p0   = blockIdx.x * 64;     // 511 tiles, 511*64 = 32704 exactly
    const int lane = threadIdx.x & 63;
    const int grp  = threadIdx.x >> 6;
    #pragma unroll
    for (int i = 0; i < 16; ++i) {
        int nn = grp * 16 + i;
        ts[nn][lane] = yT[nn * MPAD + p0 + lane];
    }
    __syncthreads();
    #pragma unroll
    for (int i = 0; i < 16; ++i) {
        int p = grp * 16 + i;
        if (p0 + p < NPOS) out[(p0 + p) * NCH + lane] = ts[lane][p];
    }
}

extern "C" void kernel_launch(void* const* d_in, const int* in_sizes, int n_in,
                              void* d_out, int out_size, void* d_ws, size_t ws_size,
                              hipStream_t stream)
{
    const float* X  = (const float*)d_in[0];
    const float* W0 = (const float*)d_in[1];
    const float* b0 = (const float*)d_in[2];
    const float* W1 = (const float*)d_in[3];
    const float* b1 = (const float*)d_in[4];
    const float* W2 = (const float*)d_in[5];
    const float* b2 = (const float*)d_in[6];
    float* out = (float*)d_out;

    // workspace layout (bytes)
    unsigned short* Xb  = (unsigned short*)d_ws;                          // 4,194,304
    unsigned short* W0b = (unsigned short*)((char*)d_ws + 4194304);       // 1,310,720
    unsigned short* W1b = (unsigned short*)((char*)d_ws + 5505024);       //   131,072
    float* yT = nullptr;
    size_t need = 5636096 + (size_t)NCH * MPAD * 4;                       // +8,388,608
    if (ws_size >= need) yT = (float*)((char*)d_ws + 5636096);

    prep_x <<<2048, 256, 0, stream>>>(X, Xb);
    prep_w0<<<2560, 256, 0, stream>>>(W0, W0b);
    prep_w1<<< 256, 256, 0, stream>>>(W1, W1b);
    mlp_mfma<<<dim3(64, 128), 256, 0, stream>>>(Xb, W0b, W1b, b0, b1, W2, b2, yT, out);
    if (yT) transpose_out<<<511, 256, 0, stream>>>(yT, out);
}

// Round 3
// 284.736 us; speedup vs baseline: 3.3563x; 1.0720x over previous
//
#include <hip/hip_runtime.h>

#define NCH 64
#define LAG 5
#define H0 32
#define H1 32
#define TIN 2048
#define TOUT 2044
#define NBATCH 16
#define NPOS (NBATCH*TOUT)   // 32704
#define MPAD 32768           // yT row stride (per network)
#define NTILE 128            // ceil(NPOS/256)
#define GY 32                // y-grid; tiles per block = NTILE/GY = 4

typedef __attribute__((ext_vector_type(8))) short short8;   // 8 bf16 = 4 VGPRs
typedef __attribute__((ext_vector_type(4))) float f32x4;

__device__ __forceinline__ unsigned short f2bf(float f) {
    unsigned u = __float_as_uint(f);
    u += 0x7fffu + ((u >> 16) & 1u);     // RNE
    return (unsigned short)(u >> 16);
}

// ---- fused prep: X cast | W0 repack | W1 cast ----
// blocks [0,2048):    X fp32->bf16, 4 elems/thread        (2,097,152 elems)
// blocks [2048,2560): W0 [n][h][c][l] -> [nh][l*64+c],    thread per (nh,c)
// blocks [2560,2592): W1 cast, 8 elems/thread             (65,536 elems)
__global__ __launch_bounds__(256) void prep_all(
    const float* __restrict__ X,  unsigned short* __restrict__ Xb,
    const float* __restrict__ W0, unsigned short* __restrict__ W0b,
    const float* __restrict__ W1, unsigned short* __restrict__ W1b)
{
    const int bx = blockIdx.x;
    if (bx < 2048) {
        int i = (bx * 256 + threadIdx.x) * 4;
        float4 x = *(const float4*)(X + i);
        unsigned long long v = (unsigned long long)f2bf(x.x)
                             | ((unsigned long long)f2bf(x.y) << 16)
                             | ((unsigned long long)f2bf(x.z) << 32)
                             | ((unsigned long long)f2bf(x.w) << 48);
        *(unsigned long long*)(Xb + i) = v;
    } else if (bx < 2560) {
        int j = (bx - 2048) * 256 + threadIdx.x;   // 131072 = 64 networks * 32 h * 64 c
        int nh = j >> 6, c = j & 63;
        const float* src = W0 + (size_t)j * LAG;   // [(nh*64+c)*5 + l]
        unsigned short* dst = W0b + nh * 320 + c;
        #pragma unroll
        for (int l = 0; l < LAG; ++l) dst[l * 64] = f2bf(src[l]);  // lane-contiguous per l
    } else {
        int i = ((bx - 2560) * 256 + threadIdx.x) * 8;
        float4 a = *(const float4*)(W1 + i);
        float4 b = *(const float4*)(W1 + i + 4);
        unsigned long long v0 = (unsigned long long)f2bf(a.x)
                              | ((unsigned long long)f2bf(a.y) << 16)
                              | ((unsigned long long)f2bf(a.z) << 32)
                              | ((unsigned long long)f2bf(a.w) << 48);
        unsigned long long v1 = (unsigned long long)f2bf(b.x)
                              | ((unsigned long long)f2bf(b.y) << 16)
                              | ((unsigned long long)f2bf(b.z) << 32)
                              | ((unsigned long long)f2bf(b.w) << 48);
        *(unsigned long long*)(W1b + i)     = v0;
        *(unsigned long long*)(W1b + i + 4) = v1;
    }
}

// ---- main: block = network n (blockIdx.x), sweeps 4 tiles of 256 positions ----
__global__ __launch_bounds__(256, 1) void mlp_mfma(
    const unsigned short* __restrict__ Xb,
    const unsigned short* __restrict__ W0b,
    const unsigned short* __restrict__ W1b,
    const float* __restrict__ b0, const float* __restrict__ b1,
    const float* __restrict__ W2, const float* __restrict__ b2,
    float* __restrict__ yT, float* __restrict__ out)
{
    const int n    = blockIdx.x;
    const int wave = threadIdx.x >> 6;
    const int lane = threadIdx.x & 63;
    const int quad = lane >> 4;
    const int l15  = lane & 15;

    // per-wave relayout buffer, row stride 56 ushort (16B-aligned rows, <=2-way banks)
    __shared__ __align__(16) unsigned short hs[4][64][56];   // 28,672 B

    // ---- preload all B fragments into registers (once per block) ----
    short8 B0[10][2];
    {
        const unsigned short* wp = W0b + (n * H0 + l15) * (NCH * LAG) + quad * 8;
        #pragma unroll
        for (int ks = 0; ks < 10; ++ks) {
            B0[ks][0] = *(const short8*)(wp + ks * 32);
            B0[ks][1] = *(const short8*)(wp + 16 * (NCH * LAG) + ks * 32);
        }
    }
    short8 B1[2];
    {
        const unsigned short* wp = W1b + (n * H1 + l15) * H0 + quad * 8;
        B1[0] = *(const short8*)(wp);
        B1[1] = *(const short8*)(wp + 16 * H0);
    }
    const float b0v0 = b0[n * H0 + l15],      b0v1 = b0[n * H0 + 16 + l15];
    const float b1v0 = b1[n * H1 + l15],      b1v1 = b1[n * H1 + 16 + l15];
    const float w2v0 = W2[n * H1 + l15],      w2v1 = W2[n * H1 + 16 + l15];
    const float b2s  = b2[n];

    #pragma unroll 1
    for (int tile = blockIdx.y; tile < NTILE; tile += GY) {
        const int p0 = tile * 256 + wave * 64;

        // per-m-frag X row base (lane's row m = l15), clamped for the tail tile
        const unsigned short* arow[4];
        #pragma unroll
        for (int mf = 0; mf < 4; ++mf) {
            int pos = p0 + mf * 16 + l15;
            pos = pos < NPOS ? pos : NPOS - 1;
            int b = pos / TOUT;              // const divisor -> magic mul
            int t = pos - b * TOUT;
            arow[mf] = Xb + (b * TIN + t) * NCH + quad * 8;
        }

        // ---- layer 0: [256 x 320] x [320 x 32] ----
        f32x4 acc[4][2];
        #pragma unroll
        for (int mf = 0; mf < 4; ++mf) {
            acc[mf][0] = (f32x4){ b0v0, b0v0, b0v0, b0v0 };
            acc[mf][1] = (f32x4){ b0v1, b0v1, b0v1, b0v1 };
        }
        #pragma unroll
        for (int ks = 0; ks < 10; ++ks) {
            const int off = (ks >> 1) * NCH + (ks & 1) * 32;   // k = l*64 + c
            #pragma unroll
            for (int mf = 0; mf < 4; ++mf) {
                short8 A = *(const short8*)(arow[mf] + off);
                acc[mf][0] = __builtin_amdgcn_mfma_f32_16x16x32_bf16(A, B0[ks][0], acc[mf][0], 0, 0, 0);
                acc[mf][1] = __builtin_amdgcn_mfma_f32_16x16x32_bf16(A, B0[ks][1], acc[mf][1], 0, 0, 0);
            }
        }

        // ---- relu -> bf16 -> LDS (C-layout -> A-layout, per-wave, no barrier) ----
        #pragma unroll
        for (int mf = 0; mf < 4; ++mf)
            #pragma unroll
            for (int nf = 0; nf < 2; ++nf)
                #pragma unroll
                for (int r = 0; r < 4; ++r) {
                    float v = fmaxf(acc[mf][nf][r], 0.0f);
                    hs[wave][mf * 16 + quad * 4 + r][nf * 16 + l15] = f2bf(v);
                }

        // ---- layer 1: [256 x 32] x [32 x 32] ----
        f32x4 acc1[4][2];
        #pragma unroll
        for (int mf = 0; mf < 4; ++mf) {
            acc1[mf][0] = (f32x4){ b1v0, b1v0, b1v0, b1v0 };
            acc1[mf][1] = (f32x4){ b1v1, b1v1, b1v1, b1v1 };
        }
        #pragma unroll
        for (int mf = 0; mf < 4; ++mf) {
            short8 A1 = *(const short8*)&hs[wave][mf * 16 + l15][quad * 8];
            acc1[mf][0] = __builtin_amdgcn_mfma_f32_16x16x32_bf16(A1, B1[0], acc1[mf][0], 0, 0, 0);
            acc1[mf][1] = __builtin_amdgcn_mfma_f32_16x16x32_bf16(A1, B1[1], acc1[mf][1], 0, 0, 0);
        }

        // ---- layer 2: relu -> dot(32) via VALU + 16-lane shuffle reduce ----
        #pragma unroll
        for (int mf = 0; mf < 4; ++mf)
            #pragma unroll
            for (int r = 0; r < 4; ++r) {
                float v = fmaxf(acc1[mf][0][r], 0.0f) * w2v0
                        + fmaxf(acc1[mf][1][r], 0.0f) * w2v1;
                v += __shfl_xor(v, 1, 64);
                v += __shfl_xor(v, 2, 64);
                v += __shfl_xor(v, 4, 64);
                v += __shfl_xor(v, 8, 64);
                v += b2s;
                int pos = p0 + mf * 16 + quad * 4 + r;
                if (l15 == 0 && pos < NPOS) {
                    if (yT) yT[n * MPAD + pos] = v;
                    else    out[pos * NCH + n] = v;
                }
            }
    }
}

// ---- epilogue: yT[n][pos] -> out[pos][n], 64x64 LDS tiles ----
__global__ __launch_bounds__(256) void transpose_out(const float* __restrict__ yT,
                                                     float* __restrict__ out) {
    __shared__ float ts[64][65];
    const int p0   = blockIdx.x * 64;     // 511 blocks * 64 = 32704 exactly
    const int lane = threadIdx.x & 63;
    const int grp  = threadIdx.x >> 6;
    #pragma unroll
    for (int i = 0; i < 16; ++i) {
        int nn = grp * 16 + i;
        ts[nn][lane] = yT[nn * MPAD + p0 + lane];
    }
    __syncthreads();
    #pragma unroll
    for (int i = 0; i < 16; ++i) {
        int p = grp * 16 + i;
        if (p0 + p < NPOS) out[(p0 + p) * NCH + lane] = ts[lane][p];
    }
}

extern "C" void kernel_launch(void* const* d_in, const int* in_sizes, int n_in,
                              void* d_out, int out_size, void* d_ws, size_t ws_size,
                              hipStream_t stream)
{
    const float* X  = (const float*)d_in[0];
    const float* W0 = (const float*)d_in[1];
    const float* b0 = (const float*)d_in[2];
    const float* W1 = (const float*)d_in[3];
    const float* b1 = (const float*)d_in[4];
    const float* W2 = (const float*)d_in[5];
    const float* b2 = (const float*)d_in[6];
    float* out = (float*)d_out;

    unsigned short* Xb  = (unsigned short*)d_ws;                          // 4,194,304 B
    unsigned short* W0b = (unsigned short*)((char*)d_ws + 4194304);       // 1,310,720 B
    unsigned short* W1b = (unsigned short*)((char*)d_ws + 5505024);       //   131,072 B
    float* yT = nullptr;
    size_t need = 5636096 + (size_t)NCH * MPAD * 4;                       // +8,388,608 B
    if (ws_size >= need) yT = (float*)((char*)d_ws + 5636096);

    prep_all<<<2592, 256, 0, stream>>>(X, Xb, W0, W0b, W1, W1b);
    mlp_mfma<<<dim3(64, GY), 256, 0, stream>>>(Xb, W0b, W1b, b0, b1, W2, b2, yT, out);
    if (yT) transpose_out<<<511, 256, 0, stream>>>(yT, out);
}

// Round 4
// 173.338 us; speedup vs baseline: 5.5132x; 1.6427x over previous
//
#include <hip/hip_runtime.h>

#define NCH 64
#define LAG 5
#define H0 32
#define H1 32
#define TIN 2048
#define TOUT 2044
#define NBATCH 16

#define XSTRIDE 72   // ushorts per staged X row (16B-aligned, 2-way banks max)
#define HSTRIDE 40   // ushorts per hs row

typedef __attribute__((ext_vector_type(8))) short short8;   // 8 bf16 = 4 VGPRs
typedef __attribute__((ext_vector_type(4))) float f32x4;

__device__ __forceinline__ unsigned short f2bf(float f) {
    unsigned u = __float_as_uint(f);
    u += 0x7fffu + ((u >> 16) & 1u);     // RNE
    return (unsigned short)(u >> 16);
}

// ---- fused prep: X cast | W0 repack | W1 cast | W2 cast ----
// blocks [0,2048):    X fp32->bf16, 4/thread            (2,097,152 elems)
// blocks [2048,2560): W0 [n][h][c][l] -> [nh][l*64+c]   (thread per (nh,c))
// blocks [2560,2592): W1 cast, 8/thread                 (65,536 elems)
// block  2592:        W2 cast, 8/thread                 (2,048 elems)
__global__ __launch_bounds__(256) void prep_all(
    const float* __restrict__ X,  unsigned short* __restrict__ Xb,
    const float* __restrict__ W0, unsigned short* __restrict__ W0b,
    const float* __restrict__ W1, unsigned short* __restrict__ W1b,
    const float* __restrict__ W2, unsigned short* __restrict__ W2b)
{
    const int bx = blockIdx.x;
    if (bx < 2048) {
        int i = (bx * 256 + threadIdx.x) * 4;
        float4 x = *(const float4*)(X + i);
        unsigned long long v = (unsigned long long)f2bf(x.x)
                             | ((unsigned long long)f2bf(x.y) << 16)
                             | ((unsigned long long)f2bf(x.z) << 32)
                             | ((unsigned long long)f2bf(x.w) << 48);
        *(unsigned long long*)(Xb + i) = v;
    } else if (bx < 2560) {
        int j = (bx - 2048) * 256 + threadIdx.x;   // 131072 = 64n * 32h * 64c
        int nh = j >> 6, c = j & 63;
        const float* src = W0 + (size_t)j * LAG;
        unsigned short* dst = W0b + nh * 320 + c;
        #pragma unroll
        for (int l = 0; l < LAG; ++l) dst[l * 64] = f2bf(src[l]);
    } else if (bx < 2592) {
        int i = ((bx - 2560) * 256 + threadIdx.x) * 8;
        float4 a = *(const float4*)(W1 + i);
        float4 b = *(const float4*)(W1 + i + 4);
        unsigned long long v0 = (unsigned long long)f2bf(a.x)
                              | ((unsigned long long)f2bf(a.y) << 16)
                              | ((unsigned long long)f2bf(a.z) << 32)
                              | ((unsigned long long)f2bf(a.w) << 48);
        unsigned long long v1 = (unsigned long long)f2bf(b.x)
                              | ((unsigned long long)f2bf(b.y) << 16)
                              | ((unsigned long long)f2bf(b.z) << 32)
                              | ((unsigned long long)f2bf(b.w) << 48);
        *(unsigned long long*)(W1b + i)     = v0;
        *(unsigned long long*)(W1b + i + 4) = v1;
    } else {
        int i = threadIdx.x * 8;                   // 2048 elems, one block
        float4 a = *(const float4*)(W2 + i);
        float4 b = *(const float4*)(W2 + i + 4);
        unsigned long long v0 = (unsigned long long)f2bf(a.x)
                              | ((unsigned long long)f2bf(a.y) << 16)
                              | ((unsigned long long)f2bf(a.z) << 32)
                              | ((unsigned long long)f2bf(a.w) << 48);
        unsigned long long v1 = (unsigned long long)f2bf(b.x)
                              | ((unsigned long long)f2bf(b.y) << 16)
                              | ((unsigned long long)f2bf(b.z) << 32)
                              | ((unsigned long long)f2bf(b.w) << 48);
        *(unsigned long long*)(W2b + i)     = v0;
        *(unsigned long long*)(W2b + i + 4) = v1;
    }
}

// ---- main: block = (pos-tile of 256 within one batch) x (4 networks) ----
// blockIdx.x in [0,128): b = x>>3, t0 = (x&7)*256.  blockIdx.y in [0,16): nets 4y..4y+3.
__global__ __launch_bounds__(256, 1) void mlp_mfma(
    const unsigned short* __restrict__ Xb,
    const unsigned short* __restrict__ W0b,
    const unsigned short* __restrict__ W1b,
    const unsigned short* __restrict__ W2b,
    const float* __restrict__ b0, const float* __restrict__ b1,
    const float* __restrict__ b2, float* __restrict__ out)
{
    __shared__ __align__(16) unsigned short xs[260 * XSTRIDE];   // 37,440 B
    __shared__ __align__(16) unsigned short hs[4 * 64 * HSTRIDE];// 20,480 B
    __shared__ __align__(16) float yt[256][4];                   //  4,096 B

    const int tileid = blockIdx.x;
    const int ng     = blockIdx.y;
    const int b      = tileid >> 3;
    const int t0     = (tileid & 7) * 256;
    const int tid    = threadIdx.x;
    const int wave   = tid >> 6;
    const int lane   = tid & 63;
    const int quad   = lane >> 4;
    const int l15    = lane & 15;

    // ---- stage X tile: rows t0..t0+rows-1 of batch b (contiguous) ----
    const unsigned short* src = Xb + ((size_t)(b * TIN + t0)) * NCH;
    const int rows = (t0 == 1792) ? 256 : 260;
    for (int s = tid; s < rows * 8; s += 256) {
        int r = s >> 3, cp = s & 7;
        short8 v = *(const short8*)(src + s * 8);
        *(short8*)&xs[r * XSTRIDE + cp * 8] = v;
    }
    __syncthreads();

    const int vmax = (t0 == 1792) ? 251 : 255;   // clamp dup rows on last tile
    int rowoff[4];
    #pragma unroll
    for (int mf = 0; mf < 4; ++mf) {
        int i = wave * 64 + mf * 16 + l15;
        i = i < vmax ? i : vmax;
        rowoff[mf] = i * XSTRIDE + quad * 8;
    }
    unsigned short* hrow = hs + wave * (64 * HSTRIDE);

    #pragma unroll 1
    for (int g = 0; g < 4; ++g) {
        const int n = ng * 4 + g;

        // ---- per-net B fragments / biases ----
        short8 B0[10][2];
        const unsigned short* wp0 = W0b + (n * H0 + l15) * (NCH * LAG) + quad * 8;
        #pragma unroll
        for (int ks = 0; ks < 10; ++ks) {
            B0[ks][0] = *(const short8*)(wp0 + ks * 32);
            B0[ks][1] = *(const short8*)(wp0 + 16 * (NCH * LAG) + ks * 32);
        }
        short8 B1[2];
        const unsigned short* wp1 = W1b + (n * H1 + l15) * H0 + quad * 8;
        B1[0] = *(const short8*)(wp1);
        B1[1] = *(const short8*)(wp1 + 16 * H0);
        short8 B2 = *(const short8*)(W2b + n * H1 + quad * 8);
        const float b0v0 = b0[n * H0 + l15], b0v1 = b0[n * H0 + 16 + l15];
        const float b1v0 = b1[n * H1 + l15], b1v1 = b1[n * H1 + 16 + l15];
        const float b2s  = b2[n];

        // ---- layer 0: A from LDS, B in regs ----
        f32x4 acc[4][2];
        #pragma unroll
        for (int mf = 0; mf < 4; ++mf) {
            acc[mf][0] = (f32x4){ b0v0, b0v0, b0v0, b0v0 };
            acc[mf][1] = (f32x4){ b0v1, b0v1, b0v1, b0v1 };
        }
        #pragma unroll
        for (int ks = 0; ks < 10; ++ks) {
            const int xoff = (ks >> 1) * XSTRIDE + (ks & 1) * 32;
            #pragma unroll
            for (int mf = 0; mf < 4; ++mf) {
                short8 A = *(const short8*)&xs[rowoff[mf] + xoff];
                acc[mf][0] = __builtin_amdgcn_mfma_f32_16x16x32_bf16(A, B0[ks][0], acc[mf][0], 0, 0, 0);
                acc[mf][1] = __builtin_amdgcn_mfma_f32_16x16x32_bf16(A, B0[ks][1], acc[mf][1], 0, 0, 0);
            }
        }

        // ---- relu -> bf16 -> hs (C-layout -> A-layout, per-wave) ----
        #pragma unroll
        for (int mf = 0; mf < 4; ++mf)
            #pragma unroll
            for (int nf = 0; nf < 2; ++nf)
                #pragma unroll
                for (int r = 0; r < 4; ++r)
                    hrow[(mf * 16 + quad * 4 + r) * HSTRIDE + nf * 16 + l15] =
                        f2bf(fmaxf(acc[mf][nf][r], 0.0f));

        // ---- layer 1 ----
        f32x4 acc1[4][2];
        #pragma unroll
        for (int mf = 0; mf < 4; ++mf) {
            acc1[mf][0] = (f32x4){ b1v0, b1v0, b1v0, b1v0 };
            acc1[mf][1] = (f32x4){ b1v1, b1v1, b1v1, b1v1 };
        }
        #pragma unroll
        for (int mf = 0; mf < 4; ++mf) {
            short8 A1 = *(const short8*)&hrow[(mf * 16 + l15) * HSTRIDE + quad * 8];
            acc1[mf][0] = __builtin_amdgcn_mfma_f32_16x16x32_bf16(A1, B1[0], acc1[mf][0], 0, 0, 0);
            acc1[mf][1] = __builtin_amdgcn_mfma_f32_16x16x32_bf16(A1, B1[1], acc1[mf][1], 0, 0, 0);
        }

        // ---- relu -> bf16 -> hs (reuse; same-wave in-order LDS) ----
        #pragma unroll
        for (int mf = 0; mf < 4; ++mf)
            #pragma unroll
            for (int nf = 0; nf < 2; ++nf)
                #pragma unroll
                for (int r = 0; r < 4; ++r)
                    hrow[(mf * 16 + quad * 4 + r) * HSTRIDE + nf * 16 + l15] =
                        f2bf(fmaxf(acc1[mf][nf][r], 0.0f));

        // ---- layer 2 as MFMA: B2 broadcast in every column -> C[m][*] = y[m] ----
        #pragma unroll
        for (int mf = 0; mf < 4; ++mf) {
            short8 A2 = *(const short8*)&hrow[(mf * 16 + l15) * HSTRIDE + quad * 8];
            f32x4 c2 = (f32x4){ b2s, b2s, b2s, b2s };
            c2 = __builtin_amdgcn_mfma_f32_16x16x32_bf16(A2, B2, c2, 0, 0, 0);
            // writer lane for row m=l15: quad == l15>>2, reg r = l15&3
            float v = (l15 & 2) ? ((l15 & 1) ? c2[3] : c2[2])
                                : ((l15 & 1) ? c2[1] : c2[0]);
            if (quad == (l15 >> 2))
                yt[wave * 64 + mf * 16 + l15][g] = v;
        }
    }
    __syncthreads();

    // ---- coalesced output: float4 per thread ----
    int t = t0 + tid;
    if (t < TOUT) {
        float4 v = *(const float4*)yt[tid];
        *(float4*)&out[((size_t)(b * TOUT + t)) * NCH + ng * 4] = v;
    }
}

extern "C" void kernel_launch(void* const* d_in, const int* in_sizes, int n_in,
                              void* d_out, int out_size, void* d_ws, size_t ws_size,
                              hipStream_t stream)
{
    const float* X  = (const float*)d_in[0];
    const float* W0 = (const float*)d_in[1];
    const float* b0 = (const float*)d_in[2];
    const float* W1 = (const float*)d_in[3];
    const float* b1 = (const float*)d_in[4];
    const float* W2 = (const float*)d_in[5];
    const float* b2 = (const float*)d_in[6];
    float* out = (float*)d_out;

    unsigned short* Xb  = (unsigned short*)d_ws;                       // 4,194,304 B
    unsigned short* W0b = (unsigned short*)((char*)d_ws + 4194304);    // 1,310,720 B
    unsigned short* W1b = (unsigned short*)((char*)d_ws + 5505024);    //   131,072 B
    unsigned short* W2b = (unsigned short*)((char*)d_ws + 5636096);    //     4,096 B

    prep_all<<<2593, 256, 0, stream>>>(X, Xb, W0, W0b, W1, W1b, W2, W2b);
    mlp_mfma<<<dim3(128, 16), 256, 0, stream>>>(Xb, W0b, W1b, W2b, b0, b1, b2, out);
}

// Round 5
// 136.506 us; speedup vs baseline: 7.0008x; 1.2698x over previous
//
#include <hip/hip_runtime.h>

#define NCH 64
#define LAG 5
#define H0 32
#define H1 32
#define TIN 2048
#define TOUT 2044
#define NBATCH 16

#define XSTRIDE 72   // ushorts per staged X row (16B-aligned rows)
#define HSTRIDE 40   // ushorts per hs row

typedef __attribute__((ext_vector_type(8))) short short8;   // 8 bf16 = 4 VGPRs
typedef __attribute__((ext_vector_type(4))) float f32x4;

__device__ __forceinline__ unsigned short f2bf(float f) {
    unsigned u = __float_as_uint(f);
    u += 0x7fffu + ((u >> 16) & 1u);     // RNE
    return (unsigned short)(u >> 16);
}

// ---- weights-only prep ----
// blocks [0,512):   W0 [n][h][c][l] -> W0b[nh][k=l*64+c]  (thread per (nh,c))
// blocks [512,544): W1 cast, 8/thread (65,536 elems)
// block  544:       W2 cast, 8/thread (2,048 elems)
__global__ __launch_bounds__(256) void prep_w(
    const float* __restrict__ W0, unsigned short* __restrict__ W0b,
    const float* __restrict__ W1, unsigned short* __restrict__ W1b,
    const float* __restrict__ W2, unsigned short* __restrict__ W2b)
{
    const int bx = blockIdx.x;
    if (bx < 512) {
        int j = bx * 256 + threadIdx.x;            // 131072 = 64n * 32h * 64c
        int nh = j >> 6, c = j & 63;
        const float* src = W0 + (size_t)j * LAG;
        unsigned short* dst = W0b + nh * 320 + c;
        #pragma unroll
        for (int l = 0; l < LAG; ++l) dst[l * 64] = f2bf(src[l]);
    } else if (bx < 544) {
        int i = ((bx - 512) * 256 + threadIdx.x) * 8;
        float4 a = *(const float4*)(W1 + i);
        float4 b = *(const float4*)(W1 + i + 4);
        unsigned long long v0 = (unsigned long long)f2bf(a.x)
                              | ((unsigned long long)f2bf(a.y) << 16)
                              | ((unsigned long long)f2bf(a.z) << 32)
                              | ((unsigned long long)f2bf(a.w) << 48);
        unsigned long long v1 = (unsigned long long)f2bf(b.x)
                              | ((unsigned long long)f2bf(b.y) << 16)
                              | ((unsigned long long)f2bf(b.z) << 32)
                              | ((unsigned long long)f2bf(b.w) << 48);
        *(unsigned long long*)(W1b + i)     = v0;
        *(unsigned long long*)(W1b + i + 4) = v1;
    } else {
        int i = threadIdx.x * 8;
        float4 a = *(const float4*)(W2 + i);
        float4 b = *(const float4*)(W2 + i + 4);
        unsigned long long v0 = (unsigned long long)f2bf(a.x)
                              | ((unsigned long long)f2bf(a.y) << 16)
                              | ((unsigned long long)f2bf(a.z) << 32)
                              | ((unsigned long long)f2bf(a.w) << 48);
        unsigned long long v1 = (unsigned long long)f2bf(b.x)
                              | ((unsigned long long)f2bf(b.y) << 16)
                              | ((unsigned long long)f2bf(b.z) << 32)
                              | ((unsigned long long)f2bf(b.w) << 48);
        *(unsigned long long*)(W2b + i)     = v0;
        *(unsigned long long*)(W2b + i + 4) = v1;
    }
}

// ---- main: block = 256-pos tile (within one batch) x 4 nets; WAVE = NET ----
// blockIdx.x in [0,128): b = x>>3, t0 = (x&7)*256.  blockIdx.y in [0,16).
// Wave w handles net ng*4+w for ALL 256 positions (4 chunks of 64 rows):
// B-fragments loaded ONCE per wave, X tile cast+staged to LDS by the block.
__global__ __launch_bounds__(256, 2) void mlp_mfma(
    const float* __restrict__ X,
    const unsigned short* __restrict__ W0b,
    const unsigned short* __restrict__ W1b,
    const unsigned short* __restrict__ W2b,
    const float* __restrict__ b0, const float* __restrict__ b1,
    const float* __restrict__ b2, float* __restrict__ out)
{
    __shared__ __align__(16) unsigned short xs[260 * XSTRIDE];     // 37,440 B
    __shared__ __align__(16) unsigned short hs[4][64 * HSTRIDE];   // 20,480 B
    __shared__ __align__(16) float yt[256][4];                     //  4,096 B

    const int tileid = blockIdx.x;
    const int ng     = blockIdx.y;
    const int b      = tileid >> 3;
    const int t0     = (tileid & 7) * 256;
    const int tid    = threadIdx.x;
    const int wave   = tid >> 6;
    const int lane   = tid & 63;
    const int quad   = lane >> 4;
    const int l15    = lane & 15;

    // ---- stage X tile: fp32 -> bf16 -> LDS (coalesced float4 reads, b64 writes) ----
    const float* src = X + ((size_t)(b * TIN + t0)) * NCH;
    const int rows = (t0 == 1792) ? 256 : 260;
    for (int s = tid; s < rows * 16; s += 256) {
        int r = s >> 4, seg = s & 15;
        float4 x = *(const float4*)(src + s * 4);   // s*4 = r*64 + seg*4
        unsigned long long v = (unsigned long long)f2bf(x.x)
                             | ((unsigned long long)f2bf(x.y) << 16)
                             | ((unsigned long long)f2bf(x.z) << 32)
                             | ((unsigned long long)f2bf(x.w) << 48);
        *(unsigned long long*)&xs[r * XSTRIDE + seg * 4] = v;
    }
    __syncthreads();

    // ---- per-wave net: B fragments / biases, loaded once ----
    const int n = ng * 4 + wave;
    short8 B0[10][2];
    const unsigned short* wp0 = W0b + (n * H0 + l15) * (NCH * LAG) + quad * 8;
    #pragma unroll
    for (int ks = 0; ks < 10; ++ks) {
        B0[ks][0] = *(const short8*)(wp0 + ks * 32);
        B0[ks][1] = *(const short8*)(wp0 + 16 * (NCH * LAG) + ks * 32);
    }
    short8 B1[2];
    const unsigned short* wp1 = W1b + (n * H1 + l15) * H0 + quad * 8;
    B1[0] = *(const short8*)(wp1);
    B1[1] = *(const short8*)(wp1 + 16 * H0);
    short8 B2 = *(const short8*)(W2b + n * H1 + quad * 8);
    const float b0v0 = b0[n * H0 + l15], b0v1 = b0[n * H0 + 16 + l15];
    const float b1v0 = b1[n * H1 + l15], b1v1 = b1[n * H1 + 16 + l15];
    const float b2s  = b2[n];

    const int vmax = (t0 == 1792) ? 251 : 255;     // clamp dup rows on last tile
    unsigned short* hrow = hs[wave];

    #pragma unroll 1
    for (int chunk = 0; chunk < 4; ++chunk) {
        int rowoff[4];
        #pragma unroll
        for (int mf = 0; mf < 4; ++mf) {
            int i = chunk * 64 + mf * 16 + l15;
            i = i < vmax ? i : vmax;
            rowoff[mf] = i * XSTRIDE + quad * 8;
        }

        // ---- layer 0: A from xs, B in regs ----
        f32x4 acc[4][2];
        #pragma unroll
        for (int mf = 0; mf < 4; ++mf) {
            acc[mf][0] = (f32x4){ b0v0, b0v0, b0v0, b0v0 };
            acc[mf][1] = (f32x4){ b0v1, b0v1, b0v1, b0v1 };
        }
        #pragma unroll
        for (int ks = 0; ks < 10; ++ks) {
            const int xoff = (ks >> 1) * XSTRIDE + (ks & 1) * 32;
            #pragma unroll
            for (int mf = 0; mf < 4; ++mf) {
                short8 A = *(const short8*)&xs[rowoff[mf] + xoff];
                acc[mf][0] = __builtin_amdgcn_mfma_f32_16x16x32_bf16(A, B0[ks][0], acc[mf][0], 0, 0, 0);
                acc[mf][1] = __builtin_amdgcn_mfma_f32_16x16x32_bf16(A, B0[ks][1], acc[mf][1], 0, 0, 0);
            }
        }

        // ---- relu -> bf16 -> hs (C-layout -> A-layout, same-wave, no barrier) ----
        #pragma unroll
        for (int mf = 0; mf < 4; ++mf)
            #pragma unroll
            for (int nf = 0; nf < 2; ++nf)
                #pragma unroll
                for (int r = 0; r < 4; ++r)
                    hrow[(mf * 16 + quad * 4 + r) * HSTRIDE + nf * 16 + l15] =
                        f2bf(fmaxf(acc[mf][nf][r], 0.0f));

        // ---- layer 1 ----
        f32x4 acc1[4][2];
        #pragma unroll
        for (int mf = 0; mf < 4; ++mf) {
            acc1[mf][0] = (f32x4){ b1v0, b1v0, b1v0, b1v0 };
            acc1[mf][1] = (f32x4){ b1v1, b1v1, b1v1, b1v1 };
        }
        #pragma unroll
        for (int mf = 0; mf < 4; ++mf) {
            short8 A1 = *(const short8*)&hrow[(mf * 16 + l15) * HSTRIDE + quad * 8];
            acc1[mf][0] = __builtin_amdgcn_mfma_f32_16x16x32_bf16(A1, B1[0], acc1[mf][0], 0, 0, 0);
            acc1[mf][1] = __builtin_amdgcn_mfma_f32_16x16x32_bf16(A1, B1[1], acc1[mf][1], 0, 0, 0);
        }

        // ---- relu -> bf16 -> hs (reuse) ----
        #pragma unroll
        for (int mf = 0; mf < 4; ++mf)
            #pragma unroll
            for (int nf = 0; nf < 2; ++nf)
                #pragma unroll
                for (int r = 0; r < 4; ++r)
                    hrow[(mf * 16 + quad * 4 + r) * HSTRIDE + nf * 16 + l15] =
                        f2bf(fmaxf(acc1[mf][nf][r], 0.0f));

        // ---- layer 2 as MFMA (B2 broadcast across cols) ----
        #pragma unroll
        for (int mf = 0; mf < 4; ++mf) {
            short8 A2 = *(const short8*)&hrow[(mf * 16 + l15) * HSTRIDE + quad * 8];
            f32x4 c2 = (f32x4){ b2s, b2s, b2s, b2s };
            c2 = __builtin_amdgcn_mfma_f32_16x16x32_bf16(A2, B2, c2, 0, 0, 0);
            float v = (l15 & 2) ? ((l15 & 1) ? c2[3] : c2[2])
                                : ((l15 & 1) ? c2[1] : c2[0]);
            if (quad == (l15 >> 2))
                yt[chunk * 64 + mf * 16 + l15][wave] = v;
        }
    }
    __syncthreads();   // yt columns written by different waves

    // ---- coalesced output: float4 per thread ----
    int t = t0 + tid;
    if (t < TOUT) {
        float4 v = *(const float4*)yt[tid];
        *(float4*)&out[((size_t)(b * TOUT + t)) * NCH + ng * 4] = v;
    }
}

extern "C" void kernel_launch(void* const* d_in, const int* in_sizes, int n_in,
                              void* d_out, int out_size, void* d_ws, size_t ws_size,
                              hipStream_t stream)
{
    const float* X  = (const float*)d_in[0];
    const float* W0 = (const float*)d_in[1];
    const float* b0 = (const float*)d_in[2];
    const float* W1 = (const float*)d_in[3];
    const float* b1 = (const float*)d_in[4];
    const float* W2 = (const float*)d_in[5];
    const float* b2 = (const float*)d_in[6];
    float* out = (float*)d_out;

    unsigned short* W0b = (unsigned short*)d_ws;                    // 1,310,720 B
    unsigned short* W1b = (unsigned short*)((char*)d_ws + 1310720); //   131,072 B
    unsigned short* W2b = (unsigned short*)((char*)d_ws + 1441792); //     4,096 B

    prep_w<<<545, 256, 0, stream>>>(W0, W0b, W1, W1b, W2, W2b);
    mlp_mfma<<<dim3(128, 16), 256, 0, stream>>>(X, W0b, W1b, W2b, b0, b1, b2, out);
}